// Round 1
// baseline (1140.199 us; speedup 1.0000x reference)
//
#include <hip/hip_runtime.h>
#include <math.h>

// Problem constants
#define M_ROWS 32768   // 32*32*32 positions
#define DIMS   256
#define KCODES 4096

// Workspace layout (in float units)
#define WS_C2      0                          // 4096 floats
#define WS_COLPART 4096                       // 256*4096 floats (per-rowtile colmin partials)
#define WS_RMV     (4096 + 256*4096)          // 2*32768 floats (rowmin value per col-half)
#define WS_RMK     (WS_RMV + 2*32768)         // 2*32768 ints   (rowmin code idx per col-half)
#define WS_ACC     (WS_RMK + 2*32768)         // 2 floats: [mse_sum, ent_sum]

// ---------------------------------------------------------------------------
// c2[k] = ||codebook[k]||^2.  One wave per code: 64 lanes x float4 = 256 dims.
__global__ __launch_bounds__(256) void vq_c2(const float* __restrict__ cb,
                                             float* __restrict__ c2g) {
  int w = threadIdx.x >> 6, lane = threadIdx.x & 63;
  int code = blockIdx.x * 4 + w;
  const float4* p = (const float4*)(cb + (size_t)code * DIMS);
  float4 v = p[lane];
  float s = v.x * v.x + v.y * v.y + v.z * v.z + v.w * v.w;
  #pragma unroll
  for (int off = 32; off > 0; off >>= 1) s += __shfl_down(s, off, 64);
  if (lane == 0) c2g[code] = s;
}

// ---------------------------------------------------------------------------
// Main fused kernel: fp32 tiled GEMM (V . C^T) with fused distance epilogue,
// block-local row argmin, and per-rowtile column-min partials.
// grid 512: blockIdx>>1 = row tile (128 rows), blockIdx&1 = column half (2048).
__global__ __launch_bounds__(256) void vq_main(const float* __restrict__ V,
                                               const float* __restrict__ CB,
                                               const float* __restrict__ c2g,
                                               float* __restrict__ ws) {
  __shared__ float Al[32 * 132];      // [k][row], pad 4 keeps float4 16B-aligned
  __shared__ float Bl[32 * 132];      // [k][col]
  __shared__ float v2s[128];
  __shared__ float colred[16 * 136];  // [ty][col] reduction scratch

  const int tid = threadIdx.x;
  const int tx = tid & 15, ty = tid >> 4;
  const int rt = blockIdx.x >> 1;
  const int ch = blockIdx.x & 1;
  const int rowBase = rt * 128;
  const int colHalf = ch * 2048;

  // ---- v2 for this block's 128 rows (two threads per row) ----
  {
    int row = tid >> 1, half = tid & 1;
    const float4* p = (const float4*)(V + (size_t)(rowBase + row) * DIMS + half * 128);
    float s = 0.f;
    #pragma unroll
    for (int i = 0; i < 32; ++i) {
      float4 v = p[i];
      s += v.x * v.x + v.y * v.y + v.z * v.z + v.w * v.w;
    }
    colred[row * 2 + half] = s;
  }
  __syncthreads();
  if (tid < 128) v2s[tid] = colred[tid * 2] + colred[tid * 2 + 1];
  __syncthreads();

  float rminv[8];
  int   rmink[8];
  #pragma unroll
  for (int i = 0; i < 8; ++i) { rminv[i] = 3.4e38f; rmink[i] = 0x7fffffff; }

  for (int ct = 0; ct < 16; ++ct) {
    float acc[8][8];
    #pragma unroll
    for (int i = 0; i < 8; ++i)
      #pragma unroll
      for (int j = 0; j < 8; ++j) acc[i][j] = 0.f;

    const int cTile = colHalf + ct * 128;

    for (int kc = 0; kc < 8; ++kc) {
      __syncthreads();
      // stage 128x32 chunks of A and B, transposed to [k][row]
      #pragma unroll
      for (int p = 0; p < 4; ++p) {
        int s = tid + p * 256;         // 0..1023 float4 slots
        int r = s >> 3, kg = s & 7;    // 8 float4-groups per row
        float4 av = *(const float4*)(V  + (size_t)(rowBase + r) * DIMS + kc * 32 + kg * 4);
        float4 bv = *(const float4*)(CB + (size_t)(cTile  + r) * DIMS + kc * 32 + kg * 4);
        int kk = kg * 4;
        Al[(kk + 0) * 132 + r] = av.x; Al[(kk + 1) * 132 + r] = av.y;
        Al[(kk + 2) * 132 + r] = av.z; Al[(kk + 3) * 132 + r] = av.w;
        Bl[(kk + 0) * 132 + r] = bv.x; Bl[(kk + 1) * 132 + r] = bv.y;
        Bl[(kk + 2) * 132 + r] = bv.z; Bl[(kk + 3) * 132 + r] = bv.w;
      }
      __syncthreads();
      #pragma unroll 4
      for (int k = 0; k < 32; ++k) {
        const float* ar = Al + k * 132 + ty * 8;
        const float* br = Bl + k * 132 + tx * 8;
        float4 a0 = *(const float4*)ar;
        float4 a1 = *(const float4*)(ar + 4);
        float4 b0 = *(const float4*)br;
        float4 b1 = *(const float4*)(br + 4);
        float a[8] = {a0.x, a0.y, a0.z, a0.w, a1.x, a1.y, a1.z, a1.w};
        float b[8] = {b0.x, b0.y, b0.z, b0.w, b1.x, b1.y, b1.z, b1.w};
        #pragma unroll
        for (int i = 0; i < 8; ++i)
          #pragma unroll
          for (int j = 0; j < 8; ++j) acc[i][j] = fmaf(a[i], b[j], acc[i][j]);
      }
    }

    // ---- epilogue: distances + running row-min + tile col-min ----
    float c2v[8];
    #pragma unroll
    for (int j = 0; j < 8; ++j) c2v[j] = c2g[cTile + tx * 8 + j];
    float cpart[8];
    #pragma unroll
    for (int j = 0; j < 8; ++j) cpart[j] = 3.4e38f;
    #pragma unroll
    for (int i = 0; i < 8; ++i) {
      float vv = v2s[ty * 8 + i];
      #pragma unroll
      for (int j = 0; j < 8; ++j) {
        float d = vv + c2v[j] - 2.f * acc[i][j];
        if (d < rminv[i]) { rminv[i] = d; rmink[i] = cTile + tx * 8 + j; }
        cpart[j] = fminf(cpart[j], d);
      }
    }
    #pragma unroll
    for (int j = 0; j < 8; ++j) colred[ty * 136 + tx * 8 + j] = cpart[j];
    __syncthreads();
    if (tid < 128) {
      float m = colred[tid];
      #pragma unroll
      for (int q = 1; q < 16; ++q) m = fminf(m, colred[q * 136 + tid]);
      ws[WS_COLPART + rt * 4096 + cTile + tid] = m;
    }
    // next iteration's first __syncthreads protects colred / Al / Bl
  }

  // ---- row argmin across the 16 tx threads sharing each row ----
  __syncthreads();
  float* rv = Al;
  int*   rk = (int*)Bl;
  #pragma unroll
  for (int i = 0; i < 8; ++i) {
    rv[(ty * 8 + i) * 16 + tx] = rminv[i];
    rk[(ty * 8 + i) * 16 + tx] = rmink[i];
  }
  __syncthreads();
  if (tid < 128) {
    float best = rv[tid * 16];
    int   bk   = rk[tid * 16];
    #pragma unroll
    for (int q = 1; q < 16; ++q) {
      float v = rv[tid * 16 + q];
      int   k2 = rk[tid * 16 + q];
      if (v < best || (v == best && k2 < bk)) { best = v; bk = k2; }
    }
    ws[WS_RMV + ch * 32768 + rowBase + tid] = best;
    ((int*)ws)[WS_RMK + ch * 32768 + rowBase + tid] = bk;
  }
}

// ---------------------------------------------------------------------------
// Merge col-half argmins -> token, gather codebook row, write out = x+(e-x),
// accumulate sum((e-x)^2). One wave per row.
__global__ __launch_bounds__(256) void vq_gather(const float* __restrict__ V,
                                                 const float* __restrict__ CB,
                                                 float* __restrict__ ws,
                                                 float* __restrict__ out) {
  __shared__ float psum[4];
  int w = threadIdx.x >> 6, lane = threadIdx.x & 63;
  int row = blockIdx.x * 4 + w;
  float v0 = ws[WS_RMV + row], v1 = ws[WS_RMV + 32768 + row];
  int   k0 = ((int*)ws)[WS_RMK + row], k1 = ((int*)ws)[WS_RMK + 32768 + row];
  int tok = (v1 < v0 || (v1 == v0 && k1 < k0)) ? k1 : k0;

  float4 e = *(const float4*)(CB + (size_t)tok * DIMS + lane * 4);
  float4 x = *(const float4*)(V + (size_t)row * DIMS + lane * 4);
  float dx = e.x - x.x, dy = e.y - x.y, dz = e.z - x.z, dw = e.w - x.w;
  float4 o;  // match reference fp op order: x + (e - x)
  o.x = x.x + dx; o.y = x.y + dy; o.z = x.z + dz; o.w = x.w + dw;
  *(float4*)(out + (size_t)row * DIMS + lane * 4) = o;

  float s = dx * dx + dy * dy + dz * dz + dw * dw;
  #pragma unroll
  for (int off = 32; off > 0; off >>= 1) s += __shfl_down(s, off, 64);
  if (lane == 0) psum[w] = s;
  __syncthreads();
  if (threadIdx.x == 0)
    atomicAdd(&ws[WS_ACC], psum[0] + psum[1] + psum[2] + psum[3]);
}

// ---------------------------------------------------------------------------
// Reduce colmin partials over 256 row tiles; accumulate sum of colmins.
__global__ __launch_bounds__(256) void vq_colreduce(float* __restrict__ ws) {
  __shared__ float psum[4];
  int col = blockIdx.x * 256 + threadIdx.x;
  float m = 3.4e38f;
  for (int rtb = 0; rtb < 256; ++rtb)
    m = fminf(m, ws[WS_COLPART + rtb * 4096 + col]);
  float s = m;
  #pragma unroll
  for (int off = 32; off > 0; off >>= 1) s += __shfl_down(s, off, 64);
  int w = threadIdx.x >> 6, lane = threadIdx.x & 63;
  if (lane == 0) psum[w] = s;
  __syncthreads();
  if (threadIdx.x == 0)
    atomicAdd(&ws[WS_ACC + 1], psum[0] + psum[1] + psum[2] + psum[3]);
}

// ---------------------------------------------------------------------------
__global__ void vq_finalize(const float* __restrict__ ws, float* __restrict__ out) {
  if (threadIdx.x == 0 && blockIdx.x == 0) {
    float mse = ws[WS_ACC] / 8388608.f;
    float ent = ws[WS_ACC + 1] / 4096.f;
    out[8388608] = 1.25f * mse + 0.1f * ent;
  }
}

// ---------------------------------------------------------------------------
extern "C" void kernel_launch(void* const* d_in, const int* in_sizes, int n_in,
                              void* d_out, int out_size, void* d_ws, size_t ws_size,
                              hipStream_t stream) {
  const float* V  = (const float*)d_in[0];   // [32768, 256]
  const float* CB = (const float*)d_in[1];   // [4096, 256]
  float* out = (float*)d_out;                // 8388608 emb + 1 loss
  float* ws  = (float*)d_ws;

  hipMemsetAsync(ws + WS_ACC, 0, 2 * sizeof(float), stream);
  vq_c2<<<KCODES / 4, 256, 0, stream>>>(CB, ws + WS_C2);
  vq_main<<<512, 256, 0, stream>>>(V, CB, ws + WS_C2, ws);
  vq_gather<<<M_ROWS / 4, 256, 0, stream>>>(V, CB, ws, out);
  vq_colreduce<<<KCODES / 256, 256, 0, stream>>>(ws);
  vq_finalize<<<1, 64, 0, stream>>>(ws, out);
}

// Round 2
// 549.941 us; speedup vs baseline: 2.0733x; 2.0733x over previous
//
#include <hip/hip_runtime.h>
#include <math.h>

// Problem constants
#define M_ROWS 32768   // 32*32*32 positions
#define DIMS   256
#define KCODES 4096

// Workspace layout (float units)
#define WS_V2     0                    // 32768 floats ||v||^2
#define WS_C2     32768                // 4096 floats  ||c||^2
#define WS_ROWKEY 36864                // 32768 u64 (dist_bits<<32 | code) -> 65536 float slots
#define WS_COLKEY (36864 + 65536)     // 4096 u32 (dist_bits)
#define WS_ACC    (36864 + 65536 + 4096) // 1 float: mse_sum

typedef _Float16 half8 __attribute__((ext_vector_type(8)));
typedef _Float16 half4 __attribute__((ext_vector_type(4)));
typedef float floatx4 __attribute__((ext_vector_type(4)));

#define GS 1032   // halves per k-group slab: 129 x 16B chunks (bank-staggered, 16B aligned)

// ---------------------------------------------------------------------------
// prep: ws[row] = ||row||^2 for V rows 0..32767 and CB rows 32768..36863.
__global__ __launch_bounds__(256) void vq_prep(const float* __restrict__ V,
                                               const float* __restrict__ CB,
                                               float* __restrict__ ws) {
  int w = threadIdx.x >> 6, lane = threadIdx.x & 63;
  int row = blockIdx.x * 4 + w;
  const float* src = (row < M_ROWS) ? (V + (size_t)row * DIMS)
                                    : (CB + (size_t)(row - M_ROWS) * DIMS);
  float4 v = ((const float4*)src)[lane];
  float s = v.x * v.x + v.y * v.y + v.z * v.z + v.w * v.w;
  #pragma unroll
  for (int off = 32; off > 0; off >>= 1) s += __shfl_down(s, off, 64);
  if (lane == 0) ws[row] = s;
}

// ---------------------------------------------------------------------------
// Main: f16 split-precision MFMA GEMM (dot = hi.hi' + hi.lo' + lo.hi'),
// fused distance epilogue with row-argmin (atomicMin u64) and col-min
// (atomicMin u32). Grid 8192 = 256 rowtiles x 32 coltiles, 128x128 tile.
__global__ __launch_bounds__(256) void vq_main(const float* __restrict__ V,
                                               const float* __restrict__ CB,
                                               float* __restrict__ ws) {
  __shared__ alignas(16) _Float16 Ah[4 * GS];
  __shared__ alignas(16) _Float16 Al[4 * GS];
  __shared__ alignas(16) _Float16 Bh[4 * GS];
  __shared__ alignas(16) _Float16 Bl[4 * GS];
  __shared__ float v2s[128], c2s[128];
  __shared__ float rowV[2][128];
  __shared__ int   rowI[2][128];
  __shared__ float colM[2][128];

  const int t = threadIdx.x;
  const int lane = t & 63, w = t >> 6;
  const int wm = w & 1, wn = w >> 1;         // wave grid 2x2, each 64x64
  const int q = lane >> 4, c = lane & 15;
  const int rt = blockIdx.x >> 5, ct = blockIdx.x & 31;
  const int rowBase = rt * 128, colBase = ct * 128;

  if (t < 128) v2s[t] = ws[WS_V2 + rowBase + t];
  else         c2s[t - 128] = ws[WS_C2 + colBase + (t - 128)];

  floatx4 acc[4][4];
  #pragma unroll
  for (int i = 0; i < 4; ++i)
    #pragma unroll
    for (int j = 0; j < 4; ++j) acc[i][j] = (floatx4){0.f, 0.f, 0.f, 0.f};

  for (int kc = 0; kc < 8; ++kc) {
    __syncthreads();   // also covers the v2s/c2s writes before first stage
    // ---- stage 128x32 fp32 chunks of A and B, split into hi/lo f16 ----
    #pragma unroll
    for (int p = 0; p < 4; ++p) {
      int s = t + p * 256;                  // 1024 float4 slots
      int r = s >> 3, kq = s & 7;           // row 0..127, float4 idx in 32-k
      float4 av = *(const float4*)(V  + (size_t)(rowBase + r) * DIMS + kc * 32 + kq * 4);
      float4 bv = *(const float4*)(CB + (size_t)(colBase + r) * DIMS + kc * 32 + kq * 4);
      int off = (kq >> 1) * GS + r * 8 + (kq & 1) * 4;   // halves
      half4 ahv, alv, bhv, blv;
      ahv[0] = (_Float16)av.x; ahv[1] = (_Float16)av.y;
      ahv[2] = (_Float16)av.z; ahv[3] = (_Float16)av.w;
      alv[0] = (_Float16)(av.x - (float)ahv[0]);
      alv[1] = (_Float16)(av.y - (float)ahv[1]);
      alv[2] = (_Float16)(av.z - (float)ahv[2]);
      alv[3] = (_Float16)(av.w - (float)ahv[3]);
      bhv[0] = (_Float16)bv.x; bhv[1] = (_Float16)bv.y;
      bhv[2] = (_Float16)bv.z; bhv[3] = (_Float16)bv.w;
      blv[0] = (_Float16)(bv.x - (float)bhv[0]);
      blv[1] = (_Float16)(bv.y - (float)bhv[1]);
      blv[2] = (_Float16)(bv.z - (float)bhv[2]);
      blv[3] = (_Float16)(bv.w - (float)bhv[3]);
      *(half4*)(Ah + off) = ahv;
      *(half4*)(Al + off) = alv;
      *(half4*)(Bh + off) = bhv;
      *(half4*)(Bl + off) = blv;
    }
    __syncthreads();
    // ---- fragments + MFMA ----
    half8 ah[4], al[4], bh[4], bl[4];
    #pragma unroll
    for (int f = 0; f < 4; ++f) {
      int ma = q * GS + (wm * 64 + f * 16 + c) * 8;
      int nb = q * GS + (wn * 64 + f * 16 + c) * 8;
      ah[f] = *(const half8*)(Ah + ma);
      al[f] = *(const half8*)(Al + ma);
      bh[f] = *(const half8*)(Bh + nb);
      bl[f] = *(const half8*)(Bl + nb);
    }
    #pragma unroll
    for (int fi = 0; fi < 4; ++fi)
      #pragma unroll
      for (int fj = 0; fj < 4; ++fj) {
        acc[fi][fj] = __builtin_amdgcn_mfma_f32_16x16x32_f16(ah[fi], bh[fj], acc[fi][fj], 0, 0, 0);
        acc[fi][fj] = __builtin_amdgcn_mfma_f32_16x16x32_f16(ah[fi], bl[fj], acc[fi][fj], 0, 0, 0);
        acc[fi][fj] = __builtin_amdgcn_mfma_f32_16x16x32_f16(al[fi], bh[fj], acc[fi][fj], 0, 0, 0);
      }
  }

  // ---- epilogue: distances, row-argmin, col-min ----
  // C/D layout: n = n_base + fj*16 + c ; m = m_base + fi*16 + q*4 + reg
  float cm[4] = {3.4e38f, 3.4e38f, 3.4e38f, 3.4e38f};
  #pragma unroll
  for (int fi = 0; fi < 4; ++fi) {
    #pragma unroll
    for (int r = 0; r < 4; ++r) {
      int ml = wm * 64 + fi * 16 + q * 4 + r;
      float vv = v2s[ml];
      float best = 3.4e38f; int bidx = 0x7fffffff;
      #pragma unroll
      for (int fj = 0; fj < 4; ++fj) {
        int nl = wn * 64 + fj * 16 + c;
        float d = vv + c2s[nl] - 2.f * acc[fi][fj][r];
        if (d < best) { best = d; bidx = colBase + nl; }
        cm[fj] = fminf(cm[fj], d);
      }
      // reduce over the 16 cols within the quad (lanes xor 1,2,4,8)
      #pragma unroll
      for (int off = 1; off < 16; off <<= 1) {
        float ov = __shfl_xor(best, off, 64);
        int   oi = __shfl_xor(bidx, off, 64);
        if (ov < best || (ov == best && oi < bidx)) { best = ov; bidx = oi; }
      }
      if (c == 0) { rowV[wn][ml] = best; rowI[wn][ml] = bidx; }
    }
  }
  // col-min: reduce across quads (same n, different m)
  #pragma unroll
  for (int fj = 0; fj < 4; ++fj) {
    cm[fj] = fminf(cm[fj], __shfl_xor(cm[fj], 16, 64));
    cm[fj] = fminf(cm[fj], __shfl_xor(cm[fj], 32, 64));
  }
  if (lane < 16) {
    #pragma unroll
    for (int fj = 0; fj < 4; ++fj) colM[wm][wn * 64 + fj * 16 + c] = cm[fj];
  }
  __syncthreads();
  if (t < 128) {
    // merge the two wn halves for this row, one u64 atomicMin per row
    float v0 = rowV[0][t], v1 = rowV[1][t];
    int   i0 = rowI[0][t], i1 = rowI[1][t];
    float bv = v0; int bi = i0;
    if (v1 < bv || (v1 == bv && i1 < bi)) { bv = v1; bi = i1; }
    unsigned long long key =
        ((unsigned long long)__float_as_uint(bv) << 32) | (unsigned)bi;
    atomicMin((unsigned long long*)(ws + WS_ROWKEY) + rowBase + t, key);
    // merge the two wm halves for this col, one u32 atomicMin per col
    float cv = fminf(colM[0][t], colM[1][t]);
    atomicMin((unsigned*)(ws + WS_COLKEY) + colBase + t, __float_as_uint(cv));
  }
}

// ---------------------------------------------------------------------------
// tokens from rowkey, gather codebook, out = x + (e - x), accumulate mse.
__global__ __launch_bounds__(256) void vq_gather(const float* __restrict__ V,
                                                 const float* __restrict__ CB,
                                                 float* __restrict__ ws,
                                                 float* __restrict__ out) {
  __shared__ float psum[4];
  int w = threadIdx.x >> 6, lane = threadIdx.x & 63;
  int row = blockIdx.x * 4 + w;
  unsigned long long key = ((const unsigned long long*)(ws + WS_ROWKEY))[row];
  int tok = (int)(unsigned)(key & 0xffffffffull);

  float4 e = *(const float4*)(CB + (size_t)tok * DIMS + lane * 4);
  float4 x = *(const float4*)(V + (size_t)row * DIMS + lane * 4);
  float dx = e.x - x.x, dy = e.y - x.y, dz = e.z - x.z, dw = e.w - x.w;
  float4 o;
  o.x = x.x + dx; o.y = x.y + dy; o.z = x.z + dz; o.w = x.w + dw;
  *(float4*)(out + (size_t)row * DIMS + lane * 4) = o;

  float s = dx * dx + dy * dy + dz * dz + dw * dw;
  #pragma unroll
  for (int off = 32; off > 0; off >>= 1) s += __shfl_down(s, off, 64);
  if (lane == 0) psum[w] = s;
  __syncthreads();
  if (threadIdx.x == 0)
    atomicAdd(&ws[WS_ACC], psum[0] + psum[1] + psum[2] + psum[3]);
}

// ---------------------------------------------------------------------------
// sum col-mins + final loss. One block; runs after vq_gather (stream order).
__global__ __launch_bounds__(256) void vq_final(const float* __restrict__ ws,
                                                float* __restrict__ out) {
  __shared__ float psum[4];
  const unsigned* ck = (const unsigned*)(ws + WS_COLKEY);
  float s = 0.f;
  for (int i = threadIdx.x; i < KCODES; i += 256) s += __uint_as_float(ck[i]);
  #pragma unroll
  for (int off = 32; off > 0; off >>= 1) s += __shfl_down(s, off, 64);
  int w = threadIdx.x >> 6, lane = threadIdx.x & 63;
  if (lane == 0) psum[w] = s;
  __syncthreads();
  if (threadIdx.x == 0) {
    float ent = psum[0] + psum[1] + psum[2] + psum[3];
    float mse = ws[WS_ACC] / 8388608.f;
    out[8388608] = 1.25f * mse + 0.1f * (ent / 4096.f);
  }
}

// ---------------------------------------------------------------------------
extern "C" void kernel_launch(void* const* d_in, const int* in_sizes, int n_in,
                              void* d_out, int out_size, void* d_ws, size_t ws_size,
                              hipStream_t stream) {
  const float* V  = (const float*)d_in[0];   // [32768, 256]
  const float* CB = (const float*)d_in[1];   // [4096, 256]
  float* out = (float*)d_out;                // 8388608 emb + 1 loss
  float* ws  = (float*)d_ws;

  // init: rowkey+colkey to all-ones (max), mse acc to 0
  hipMemsetAsync(ws + WS_ROWKEY, 0xFF, (65536 + 4096) * sizeof(float), stream);
  hipMemsetAsync(ws + WS_ACC, 0, sizeof(float), stream);
  vq_prep<<<(M_ROWS + KCODES) / 4, 256, 0, stream>>>(V, CB, ws);
  vq_main<<<8192, 256, 0, stream>>>(V, CB, ws);
  vq_gather<<<M_ROWS / 4, 256, 0, stream>>>(V, CB, ws, out);
  vq_final<<<1, 256, 0, stream>>>(ws, out);
}

// Round 3
// 426.104 us; speedup vs baseline: 2.6759x; 1.2906x over previous
//
#include <hip/hip_runtime.h>
#include <math.h>

// Problem constants
#define M_ROWS 32768   // 32*32*32 positions
#define DIMS   256
#define KCODES 4096
#define NTILE  16      // column tiles of 256
#define EPS_C  0.5f    // collection window vs block-row-min (hh err max ~0.1)
#define EPS_R  1.25f   // refine window (covers EPS_C + 2x f16 key rounding 0.25)

// ws layout (float units) — total ~2.3 MB (round-1 proved >4.6 MB available)
#define WS_CH     0          // 4096*256 halves = 524288 floats (codebook hi f16)
#define WS_V2     524288     // 32768 floats ||v||^2 (fp32-exact)
#define WS_C2     557056     // 4096  floats ||c||^2
#define WS_COLKEY 561152     // 4096  u32 f32-bits colmin (entropy)
#define WS_TOKEN  565248     // 32768 u32 tokens
#define WS_ACC    598016     // 1 float mse_sum

// d_out (8388609 floats) is reused as scratch before the final writes:
//   floats [0, 4194304)        : Vh   = 32768*256 f16 (inputs hi)
//   floats [4194304, 6291456)  : candG = 32768 rows * 16 tiles * 4 u32 entries
// vq_gather overwrites everything with the real output afterwards.

typedef _Float16 half8 __attribute__((ext_vector_type(8)));
typedef _Float16 half4 __attribute__((ext_vector_type(4)));
typedef float floatx4 __attribute__((ext_vector_type(4)));

__device__ inline void glds16(const void* g, void* l) {
  __builtin_amdgcn_global_load_lds(
      (const __attribute__((address_space(1))) void*)g,
      (__attribute__((address_space(3))) void*)l, 16, 0, 0);
}

// ---------------------------------------------------------------------------
// prep: f16-hi conversion of V (-> d_out scratch) and CB (-> ws), plus exact
// fp32 squared norms. One wave per row.
__global__ __launch_bounds__(256) void vq_prep(const float* __restrict__ V,
                                               const float* __restrict__ CB,
                                               float* __restrict__ ws,
                                               float* __restrict__ outbuf) {
  int w = threadIdx.x >> 6, lane = threadIdx.x & 63;
  int row = blockIdx.x * 4 + w;
  const float* src;
  _Float16* dst;
  float* nrm;
  if (row < M_ROWS) {
    src = V + (size_t)row * DIMS;
    dst = (_Float16*)outbuf + (size_t)row * DIMS;
    nrm = ws + WS_V2 + row;
  } else {
    int r = row - M_ROWS;
    src = CB + (size_t)r * DIMS;
    dst = (_Float16*)(ws + WS_CH) + (size_t)r * DIMS;
    nrm = ws + WS_C2 + r;
  }
  float4 v = ((const float4*)src)[lane];
  half4 h;
  h[0] = (_Float16)v.x; h[1] = (_Float16)v.y;
  h[2] = (_Float16)v.z; h[3] = (_Float16)v.w;
  *(half4*)(dst + lane * 4) = h;
  float s = v.x * v.x + v.y * v.y + v.z * v.z + v.w * v.w;
  #pragma unroll
  for (int off = 32; off > 0; off >>= 1) s += __shfl_down(s, off, 64);
  if (lane == 0) *nrm = s;
}

// ---------------------------------------------------------------------------
// hh GEMM: 128x256 block tile, 8 waves of 64x64, glds staging, XOR-swizzled
// LDS (2-way frag reads = free). Epilogue: two-phase candidate collection
// (block-row-min via LDS atomicMin, then window collect) + colmin (entropy).
__global__ __launch_bounds__(512) void vq_hh(const _Float16* __restrict__ Vh,
                                             const _Float16* __restrict__ Ch,
                                             const float* __restrict__ wsv2,
                                             const float* __restrict__ wsc2,
                                             unsigned* __restrict__ candG,
                                             unsigned* __restrict__ colkey) {
  __shared__ alignas(16) _Float16 Ah[128 * 32];   // 8 KB
  __shared__ alignas(16) _Float16 Bh[256 * 32];   // 16 KB
  __shared__ float v2s[128];
  __shared__ float c2s[256];
  __shared__ unsigned rowmin[128];
  __shared__ unsigned cnt[128];
  __shared__ unsigned candL[128][4];
  __shared__ float colM[2][256];

  const int t = threadIdx.x;
  const int lane = t & 63, w = t >> 6;
  const int wm = w & 1, wn = w >> 1;          // wave grid 2x4, each 64x64
  const int q = lane >> 4, c = lane & 15;
  const int rt = blockIdx.x >> 4, ct = blockIdx.x & 15;
  const int rowBase = rt * 128, colBase = ct * 256;

  if (t < 128) { v2s[t] = wsv2[rowBase + t]; rowmin[t] = 0xFFFFFFFFu; cnt[t] = 0u; }
  if (t < 256) c2s[t] = wsc2[colBase + t];
  ((unsigned*)candL)[t] = 0xFFFFFFFFu;        // 512 entries, one per thread

  floatx4 acc[4][4];
  #pragma unroll
  for (int i = 0; i < 4; ++i)
    #pragma unroll
    for (int j = 0; j < 4; ++j) acc[i][j] = (floatx4){0.f, 0.f, 0.f, 0.f};

  // staging source addresses (XOR swizzle: slot (r,j) holds k-chunk j^((r>>1)&3))
  const int rA = t >> 2, jA = (t & 3) ^ ((t >> 3) & 3);
  const _Float16* gA  = Vh + (size_t)(rowBase + rA) * DIMS + jA * 8;
  const _Float16* gB0 = Ch + (size_t)(colBase + rA) * DIMS + jA * 8;
  const _Float16* gB1 = gB0 + 128 * DIMS;
  char* lA  = (char*)Ah + w * 1024;
  char* lB0 = (char*)Bh + w * 1024;
  char* lB1 = (char*)Bh + 8192 + w * 1024;
  const int sw = (c >> 1) & 3;                // frag-read swizzle term

  for (int kc = 0; kc < 8; ++kc) {
    __syncthreads();                          // LDS reuse + (first iter) init cover
    glds16(gA, lA);
    glds16(gB0, lB0);
    glds16(gB1, lB1);
    gA += 32; gB0 += 32; gB1 += 32;
    __syncthreads();                          // vmcnt(0) drained by compiler
    half8 a[4], b[4];
    #pragma unroll
    for (int f = 0; f < 4; ++f) {
      int ra = wm * 64 + f * 16 + c;
      int rb = wn * 64 + f * 16 + c;
      a[f] = *(const half8*)(Ah + ra * 32 + (q ^ sw) * 8);
      b[f] = *(const half8*)(Bh + rb * 32 + (q ^ sw) * 8);
    }
    #pragma unroll
    for (int fi = 0; fi < 4; ++fi)
      #pragma unroll
      for (int fj = 0; fj < 4; ++fj)
        acc[fi][fj] = __builtin_amdgcn_mfma_f32_16x16x32_f16(a[fi], b[fj], acc[fi][fj], 0, 0, 0);
  }

  // ---- phase 1: block-row-min + colmin ----
  float cm[4] = {3.4e38f, 3.4e38f, 3.4e38f, 3.4e38f};
  #pragma unroll
  for (int fi = 0; fi < 4; ++fi) {
    #pragma unroll
    for (int r = 0; r < 4; ++r) {
      int ml = wm * 64 + fi * 16 + q * 4 + r;
      float vv = v2s[ml];
      float mn = 3.4e38f;
      #pragma unroll
      for (int fj = 0; fj < 4; ++fj) {
        float d = vv + c2s[wn * 64 + fj * 16 + c] - 2.f * acc[fi][fj][r];
        cm[fj] = fminf(cm[fj], d);
        mn = fminf(mn, d);
      }
      // reduce over the 16 c-lanes (same q => same row ml)
      mn = fminf(mn, __shfl_xor(mn, 1, 64));
      mn = fminf(mn, __shfl_xor(mn, 2, 64));
      mn = fminf(mn, __shfl_xor(mn, 4, 64));
      mn = fminf(mn, __shfl_xor(mn, 8, 64));
      if (c == 0) atomicMin(&rowmin[ml], __float_as_uint(mn));
    }
  }
  #pragma unroll
  for (int fj = 0; fj < 4; ++fj) {
    cm[fj] = fminf(cm[fj], __shfl_xor(cm[fj], 16, 64));
    cm[fj] = fminf(cm[fj], __shfl_xor(cm[fj], 32, 64));
  }
  if (lane < 16) {
    #pragma unroll
    for (int fj = 0; fj < 4; ++fj) colM[wm][wn * 64 + fj * 16 + c] = cm[fj];
  }
  __syncthreads();

  // ---- phase 2: collect candidates within rowmin + EPS_C ----
  #pragma unroll
  for (int fi = 0; fi < 4; ++fi) {
    #pragma unroll
    for (int r = 0; r < 4; ++r) {
      int ml = wm * 64 + fi * 16 + q * 4 + r;
      float thresh = __uint_as_float(rowmin[ml]) + EPS_C;
      float vv = v2s[ml];
      #pragma unroll
      for (int fj = 0; fj < 4; ++fj) {
        int nl = wn * 64 + fj * 16 + c;
        float d = vv + c2s[nl] - 2.f * acc[fi][fj][r];
        if (d <= thresh) {
          unsigned pos = atomicAdd(&cnt[ml], 1u);
          if (pos < 4) {
            unsigned short hb = __builtin_bit_cast(unsigned short, (_Float16)d);
            candL[ml][pos] = ((unsigned)hb << 16) | (unsigned)(colBase + nl);
          }
        }
      }
    }
  }
  __syncthreads();
  if (t < 128)
    *(uint4*)(candG + ((size_t)(rowBase + t) * NTILE + ct) * 4) = *(uint4*)candL[t];
  if (t < 256) {
    float cv = fminf(colM[0][t], colM[1][t]);
    atomicMin(&colkey[colBase + t], __float_as_uint(cv));
  }
}

// ---------------------------------------------------------------------------
// refine: per row, pick best candidate by f16 key; fp64-verify all candidates
// within EPS_R of the best (rare). One wave per row.
__global__ __launch_bounds__(256) void vq_refine(const float* __restrict__ V,
                                                 const float* __restrict__ CB,
                                                 const unsigned* __restrict__ candG,
                                                 unsigned* __restrict__ token) {
  int w = threadIdx.x >> 6, lane = threadIdx.x & 63;
  int row = blockIdx.x * 4 + w;
  unsigned e = candG[(size_t)row * 64 + lane];   // 16 tiles * 4 slots
  unsigned m = e;
  #pragma unroll
  for (int off = 1; off < 64; off <<= 1) {
    unsigned o = __shfl_xor(m, off, 64);
    m = (o < m) ? o : m;
  }
  float bestv = (float)__builtin_bit_cast(_Float16, (unsigned short)(m >> 16));
  float myv   = (float)__builtin_bit_cast(_Float16, (unsigned short)(e >> 16));
  // empty slots (0xFFFF) decode to NaN -> compare false -> excluded
  bool p = (myv <= bestv + EPS_R);
  unsigned long long mask = __ballot(p);
  int tok = (int)(m & 0xFFFFu);
  if (__popcll(mask) > 1) {
    float4 x = ((const float4*)(V + (size_t)row * DIMS))[lane];
    double bd = 1e300; int bi = 0x7FFFFFFF;
    while (mask) {
      int l = __ffsll((unsigned long long)mask) - 1;
      mask &= mask - 1;
      int idx = (int)(__shfl(e, l, 64) & 0xFFFFu);
      float4 cv = ((const float4*)(CB + (size_t)idx * DIMS))[lane];
      double dx = (double)cv.x - (double)x.x;
      double dy = (double)cv.y - (double)x.y;
      double dz = (double)cv.z - (double)x.z;
      double dw = (double)cv.w - (double)x.w;
      double s = dx * dx + dy * dy + dz * dz + dw * dw;
      #pragma unroll
      for (int off = 1; off < 64; off <<= 1) s += __shfl_xor(s, off, 64);
      if (s < bd || (s == bd && idx < bi)) { bd = s; bi = idx; }
    }
    tok = bi;
  }
  if (lane == 0) token[row] = (unsigned)tok;
}

// ---------------------------------------------------------------------------
// gather: out = x + (e - x), accumulate sum((e-x)^2). One wave per row.
__global__ __launch_bounds__(256) void vq_gather(const float* __restrict__ V,
                                                 const float* __restrict__ CB,
                                                 const unsigned* __restrict__ token,
                                                 float* __restrict__ ws,
                                                 float* __restrict__ out) {
  __shared__ float psum[4];
  int w = threadIdx.x >> 6, lane = threadIdx.x & 63;
  int row = blockIdx.x * 4 + w;
  int tok = (int)token[row];

  float4 e = *(const float4*)(CB + (size_t)tok * DIMS + lane * 4);
  float4 x = *(const float4*)(V + (size_t)row * DIMS + lane * 4);
  float dx = e.x - x.x, dy = e.y - x.y, dz = e.z - x.z, dw = e.w - x.w;
  float4 o;
  o.x = x.x + dx; o.y = x.y + dy; o.z = x.z + dz; o.w = x.w + dw;
  *(float4*)(out + (size_t)row * DIMS + lane * 4) = o;

  float s = dx * dx + dy * dy + dz * dz + dw * dw;
  #pragma unroll
  for (int off = 32; off > 0; off >>= 1) s += __shfl_down(s, off, 64);
  if (lane == 0) psum[w] = s;
  __syncthreads();
  if (threadIdx.x == 0)
    atomicAdd(&ws[WS_ACC], psum[0] + psum[1] + psum[2] + psum[3]);
}

// ---------------------------------------------------------------------------
__global__ __launch_bounds__(256) void vq_final(const float* __restrict__ ws,
                                                float* __restrict__ out) {
  __shared__ float psum[4];
  const unsigned* ck = (const unsigned*)(ws + WS_COLKEY);
  float s = 0.f;
  for (int i = threadIdx.x; i < KCODES; i += 256) s += __uint_as_float(ck[i]);
  #pragma unroll
  for (int off = 32; off > 0; off >>= 1) s += __shfl_down(s, off, 64);
  int w = threadIdx.x >> 6, lane = threadIdx.x & 63;
  if (lane == 0) psum[w] = s;
  __syncthreads();
  if (threadIdx.x == 0) {
    float ent = psum[0] + psum[1] + psum[2] + psum[3];
    float mse = ws[WS_ACC] / 8388608.f;
    out[8388608] = 1.25f * mse + 0.1f * (ent / 4096.f);
  }
}

// ---------------------------------------------------------------------------
extern "C" void kernel_launch(void* const* d_in, const int* in_sizes, int n_in,
                              void* d_out, int out_size, void* d_ws, size_t ws_size,
                              hipStream_t stream) {
  const float* V  = (const float*)d_in[0];   // [32768, 256]
  const float* CB = (const float*)d_in[1];   // [4096, 256]
  float* out = (float*)d_out;                // 8388608 emb + 1 loss
  float* ws  = (float*)d_ws;

  _Float16* Vh    = (_Float16*)out;                   // scratch in d_out
  unsigned* candG = (unsigned*)(out + 4194304);       // scratch in d_out
  unsigned* colkey = (unsigned*)(ws + WS_COLKEY);
  unsigned* token  = (unsigned*)(ws + WS_TOKEN);

  hipMemsetAsync(colkey, 0xFF, KCODES * sizeof(unsigned), stream);
  hipMemsetAsync(ws + WS_ACC, 0, sizeof(float), stream);
  vq_prep<<<(M_ROWS + KCODES) / 4, 256, 0, stream>>>(V, CB, ws, out);
  vq_hh<<<4096, 512, 0, stream>>>(Vh, (const _Float16*)(ws + WS_CH),
                                  ws + WS_V2, ws + WS_C2, candG, colkey);
  vq_refine<<<M_ROWS / 4, 256, 0, stream>>>(V, CB, candG, token);
  vq_gather<<<M_ROWS / 4, 256, 0, stream>>>(V, CB, token, ws, out);
  vq_final<<<1, 256, 0, stream>>>(ws, out);
}